// Round 1
// 388.137 us; speedup vs baseline: 1.1231x; 1.1231x over previous
//
#include <hip/hip_runtime.h>
#include <math.h>

#define NNODES 50000
#define NEDGES 800000
#define INDIM 256
#define HID 64
#define HEADS 4
#define OUTDIM 64
#define NEG_SLOPE 0.2f
#define NB ((NNODES + 1023) / 1024)   // 49 scan blocks

typedef __attribute__((ext_vector_type(4))) float f32x4;
typedef _Float16 __attribute__((ext_vector_type(4))) half4;
typedef _Float16 __attribute__((ext_vector_type(8))) half8;

// ---------------- CSR build ----------------

__global__ __launch_bounds__(256) void hist_kernel(const int* __restrict__ dst,
                                                   int* __restrict__ deg) {
    int i = blockIdx.x * 256 + threadIdx.x;
    if (i < NEDGES) atomicAdd(&deg[dst[i]], 1);
}

__global__ __launch_bounds__(256) void bsum_kernel(const int* __restrict__ deg,
                                                   int* __restrict__ bsums) {
    int b = blockIdx.x, t = threadIdx.x;
    int base = b * 1024 + t * 4;
    int s = 0;
    #pragma unroll
    for (int e = 0; e < 4; ++e) { int i = base + e; if (i < NNODES) s += deg[i]; }
    #pragma unroll
    for (int o = 32; o; o >>= 1) s += __shfl_xor(s, o);
    __shared__ int ws[4];
    int lane = t & 63, wid = t >> 6;
    if (lane == 0) ws[wid] = s;
    __syncthreads();
    if (t == 0) bsums[b] = ws[0] + ws[1] + ws[2] + ws[3];
}

__global__ __launch_bounds__(256) void scan_write_kernel(const int* __restrict__ deg,
                                                         const int* __restrict__ bsums,
                                                         int* __restrict__ offs) {
    int b = blockIdx.x, t = threadIdx.x;
    int lane = t & 63, wid = t >> 6;
    int bv = (lane < b) ? bsums[lane] : 0;    // b <= NB-1 < 64
    #pragma unroll
    for (int o = 32; o; o >>= 1) bv += __shfl_xor(bv, o);  // block global offset
    int base = b * 1024 + t * 4;
    int v[4]; int tsum = 0;
    #pragma unroll
    for (int e = 0; e < 4; ++e) {
        int i = base + e;
        v[e] = (i < NNODES) ? deg[i] : 0;
        tsum += v[e];
    }
    int p = tsum;
    #pragma unroll
    for (int o = 1; o < 64; o <<= 1) { int u = __shfl_up(p, o); if (lane >= o) p += u; }
    __shared__ int ws[4];
    if (lane == 63) ws[wid] = p;
    __syncthreads();
    int woff = 0;
    for (int i = 0; i < wid; ++i) woff += ws[i];
    int run = bv + woff + p - tsum;           // exclusive prefix for this thread
    #pragma unroll
    for (int e = 0; e < 4; ++e) {
        int i = base + e;
        if (i < NNODES) { offs[i] = run; run += v[e]; }
    }
    if (b == 0 && t == 0) offs[NNODES] = NEDGES;
}

__global__ __launch_bounds__(256) void scatter_kernel(const int* __restrict__ src,
                                                      const int* __restrict__ dst,
                                                      const int* __restrict__ offs,
                                                      int* __restrict__ cursor,
                                                      int* __restrict__ ssorted) {
    int i = blockIdx.x * 256 + threadIdx.x;
    if (i < NEDGES) {
        int d = dst[i];
        int pos = offs[d] + atomicAdd(&cursor[d], 1);
        ssorted[pos] = src[i];
    }
}

// ---------------- weight transpose -> fp16 ----------------

__global__ __launch_bounds__(256) void convert_wt_kernel(const float* __restrict__ W,
                                                         _Float16* __restrict__ Wt,
                                                         int K, int N) {
    int idx = blockIdx.x * 256 + threadIdx.x;
    if (idx >= K * N) return;
    int k = idx / N, n = idx - k * N;
    Wt[n * K + k] = (_Float16)W[idx];
}

// ---------------- fp16 MFMA GEMM, LDS-free, 128x(BN) tile ----------------
// ELR=1 (BN=128): wave's 64 cols = one head -> el/er written HEAD-MAJOR
//   el[h*M+row] (consumed by fused spmm1 pre-pass).
// ELR=2 (BN=64): single head over all 64 cols; per-wn partial dot + 1KB LDS
//   combine -> el[row], er[row].

template <int BN, bool AFP16, int ELR>
__global__ __launch_bounds__(256) void gemm_f16_kernel(
        const float* __restrict__ Af, const _Float16* __restrict__ Ah,
        const _Float16* __restrict__ Bt,
        _Float16* __restrict__ C,
        const float* __restrict__ al, const float* __restrict__ ar,
        float* __restrict__ el, float* __restrict__ er,
        int M, int N) {
    constexpr int K = 256;
    constexpr int NT = BN / 32;       // 16-wide n-tiles per wave
    int t = threadIdx.x;
    int lane = t & 63, w = t >> 6;
    int wm = w >> 1, wn = w & 1;
    int lr = lane & 15, quad = lane >> 4;
    int m0 = blockIdx.y * 128, n0 = blockIdx.x * BN;

    f32x4 acc[4][NT];
    #pragma unroll
    for (int i = 0; i < 4; ++i)
        #pragma unroll
        for (int j = 0; j < NT; ++j) acc[i][j] = (f32x4){0.f, 0.f, 0.f, 0.f};

    int arow[4];
    #pragma unroll
    for (int i = 0; i < 4; ++i) {
        int r = m0 + wm * 64 + i * 16 + lr;
        arow[i] = (r < M) ? r : (M - 1);
    }
    int brow[NT];
    #pragma unroll
    for (int j = 0; j < NT; ++j) brow[j] = n0 + wn * NT * 16 + j * 16 + lr;

    #pragma unroll
    for (int kk = 0; kk < K; kk += 32) {
        half8 a[4], b[NT];
        if (AFP16) {
            #pragma unroll
            for (int i = 0; i < 4; ++i)
                a[i] = *(const half8*)(Ah + (size_t)arow[i] * K + kk + quad * 8);
        } else {
            #pragma unroll
            for (int i = 0; i < 4; ++i) {
                const float* ap = Af + (size_t)arow[i] * K + kk + quad * 8;
                float4 f0 = *(const float4*)ap;
                float4 f1 = *(const float4*)(ap + 4);
                a[i][0] = (_Float16)f0.x; a[i][1] = (_Float16)f0.y;
                a[i][2] = (_Float16)f0.z; a[i][3] = (_Float16)f0.w;
                a[i][4] = (_Float16)f1.x; a[i][5] = (_Float16)f1.y;
                a[i][6] = (_Float16)f1.z; a[i][7] = (_Float16)f1.w;
            }
        }
        #pragma unroll
        for (int j = 0; j < NT; ++j)
            b[j] = *(const half8*)(Bt + (size_t)brow[j] * K + kk + quad * 8);
        #pragma unroll
        for (int i = 0; i < 4; ++i)
            #pragma unroll
            for (int j = 0; j < NT; ++j)
                acc[i][j] = __builtin_amdgcn_mfma_f32_16x16x32_f16(a[i], b[j], acc[i][j], 0, 0, 0);
    }
    #pragma unroll
    for (int i = 0; i < 4; ++i) {
        #pragma unroll
        for (int r = 0; r < 4; ++r) {
            int row = m0 + wm * 64 + i * 16 + quad * 4 + r;
            if (row < M) {
                #pragma unroll
                for (int j = 0; j < NT; ++j)
                    C[(size_t)row * N + n0 + wn * NT * 16 + j * 16 + lr] =
                        (_Float16)acc[i][j][r];
            }
        }
    }
    if constexpr (ELR == 1) {
        int h = n0 / 64 + wn;
        float alh[NT], arh[NT];
        #pragma unroll
        for (int j = 0; j < NT; ++j) {
            alh[j] = al[h * 64 + j * 16 + lr];
            arh[j] = ar[h * 64 + j * 16 + lr];
        }
        #pragma unroll
        for (int i = 0; i < 4; ++i) {
            #pragma unroll
            for (int r = 0; r < 4; ++r) {
                float pel = 0.f, per = 0.f;
                #pragma unroll
                for (int j = 0; j < NT; ++j) {
                    pel = fmaf(acc[i][j][r], alh[j], pel);
                    per = fmaf(acc[i][j][r], arh[j], per);
                }
                #pragma unroll
                for (int o = 1; o < 16; o <<= 1) {
                    pel += __shfl_xor(pel, o);
                    per += __shfl_xor(per, o);
                }
                if (lr == 0) {
                    int row = m0 + wm * 64 + i * 16 + quad * 4 + r;
                    if (row < M) {
                        el[(size_t)h * M + row] = pel;
                        er[(size_t)h * M + row] = per;
                    }
                }
            }
        }
    }
    if constexpr (ELR == 2) {
        __shared__ float elbuf[128], erbuf[128];
        float alv[NT], arv[NT];
        #pragma unroll
        for (int j = 0; j < NT; ++j) {
            alv[j] = al[wn * NT * 16 + j * 16 + lr];
            arv[j] = ar[wn * NT * 16 + j * 16 + lr];
        }
        float pel_s[4][4], per_s[4][4];
        #pragma unroll
        for (int i = 0; i < 4; ++i) {
            #pragma unroll
            for (int r = 0; r < 4; ++r) {
                float pel = 0.f, per = 0.f;
                #pragma unroll
                for (int j = 0; j < NT; ++j) {
                    pel = fmaf(acc[i][j][r], alv[j], pel);
                    per = fmaf(acc[i][j][r], arv[j], per);
                }
                #pragma unroll
                for (int o = 1; o < 16; o <<= 1) {
                    pel += __shfl_xor(pel, o);
                    per += __shfl_xor(per, o);
                }
                pel_s[i][r] = pel; per_s[i][r] = per;
            }
        }
        if (wn == 1 && lr == 0) {
            #pragma unroll
            for (int i = 0; i < 4; ++i)
                #pragma unroll
                for (int r = 0; r < 4; ++r) {
                    int rl = wm * 64 + i * 16 + quad * 4 + r;
                    elbuf[rl] = pel_s[i][r];
                    erbuf[rl] = per_s[i][r];
                }
        }
        __syncthreads();
        if (wn == 0 && lr == 0) {
            #pragma unroll
            for (int i = 0; i < 4; ++i)
                #pragma unroll
                for (int r = 0; r < 4; ++r) {
                    int rl = wm * 64 + i * 16 + quad * 4 + r;
                    int row = m0 + rl;
                    if (row < M) {
                        el[row] = pel_s[i][r] + elbuf[rl];
                        er[row] = per_s[i][r] + erbuf[rl];
                    }
                }
        }
    }
}

// ---------------- fused softmax + weighted aggregation (layer 1) ----------
// R12: wave == (node, head). No LDS, no __syncthreads, no online-softmax
// merge. Fast path (deg <= 64, always hit for this graph: mean deg 16):
// lane l holds edge l's (sj, p) in registers; two shuffle reductions
// (max, sum); aggregation broadcasts (sj, p) via __shfl and accumulates
// 8 edges x 64 dims per step with half8 loads; 1/s deferred to epilogue.

__global__ __launch_bounds__(256) void spmm1_kernel(const _Float16* __restrict__ feat,
                                                    const float* __restrict__ elh,  // [4][N]
                                                    const float* __restrict__ erh,  // [4][N]
                                                    const int* __restrict__ offs,
                                                    const int* __restrict__ ssorted,
                                                    _Float16* __restrict__ h1) {
    int n = blockIdx.x;
    int g = threadIdx.x >> 6;        // wave = head
    int l = threadIdx.x & 63;
    int e8 = l >> 3, li = l & 7;     // 8 edge slots x 8 half8 chunks (64 dims)
    int start = offs[n], end = offs[n + 1];
    int cnt = end - start;
    const float* elg = elh + (size_t)g * NNODES;
    float erg = erh[(size_t)g * NNODES + n];
    const half8* f8 = (const half8*)feat;   // node stride 32 half8s
    float acc[8];
    #pragma unroll
    for (int i = 0; i < 8; ++i) acc[i] = 0.f;
    float s;
    if (cnt <= 64) {
        int sj = 0; float e = -INFINITY;
        if (l < cnt) {
            sj = ssorted[start + l];
            float t = elg[sj] + erg;
            e = t > 0.f ? t : NEG_SLOPE * t;
        }
        float m = e;
        #pragma unroll
        for (int o = 1; o < 64; o <<= 1) m = fmaxf(m, __shfl_xor(m, o));
        float p = (l < cnt) ? __expf(e - m) : 0.f;
        s = p;
        #pragma unroll
        for (int o = 1; o < 64; o <<= 1) s += __shfl_xor(s, o);
        for (int j = 0; j < cnt; j += 8) {
            int jj = j + e8;                 // inactive slots: p=0 masks them
            int sb = __shfl(sj, jj);
            float wb = __shfl(p, jj);
            half8 f = f8[(size_t)sb * 32 + g * 8 + li];
            #pragma unroll
            for (int i = 0; i < 8; ++i) acc[i] = fmaf(wb, (float)f[i], acc[i]);
        }
    } else {
        // generic two-pass fallback (deg > 64): max pass, then exp+aggregate
        float m = -INFINITY;
        for (int b = start + l; b < end; b += 64) {
            int sj2 = ssorted[b];
            float t = elg[sj2] + erg;
            t = t > 0.f ? t : NEG_SLOPE * t;
            m = fmaxf(m, t);
        }
        #pragma unroll
        for (int o = 1; o < 64; o <<= 1) m = fmaxf(m, __shfl_xor(m, o));
        s = 0.f;
        for (int base = start; base < end; base += 64) {
            int c = min(64, end - base);
            int sj2 = 0; float p = 0.f;
            if (l < c) {
                sj2 = ssorted[base + l];
                float t = elg[sj2] + erg;
                t = t > 0.f ? t : NEG_SLOPE * t;
                p = __expf(t - m);
            }
            s += p;
            for (int j = 0; j < c; j += 8) {
                int jj = j + e8;
                int sb = __shfl(sj2, jj);
                float wb = __shfl(p, jj);
                half8 f = f8[(size_t)sb * 32 + g * 8 + li];
                #pragma unroll
                for (int i = 0; i < 8; ++i) acc[i] = fmaf(wb, (float)f[i], acc[i]);
            }
        }
        #pragma unroll
        for (int o = 1; o < 64; o <<= 1) s += __shfl_xor(s, o);
    }
    // reduce the 8 edge-slot partials (lanes differing in bits 3..5)
    #pragma unroll
    for (int o = 8; o < 64; o <<= 1) {
        #pragma unroll
        for (int i = 0; i < 8; ++i) acc[i] += __shfl_xor(acc[i], o);
    }
    if (e8 == 0) {
        float inv = s > 0.f ? 1.f / s : 0.f;
        half8 hv;
        #pragma unroll
        for (int i = 0; i < 8; ++i) {
            float v = acc[i] * inv;
            v = v > 0.f ? v : __expf(v) - 1.f;   // ELU
            hv[i] = (_Float16)v;
        }
        *(half8*)&h1[(size_t)n * 256 + g * 64 + li * 8] = hv;
    }
}

// ---------------- fused softmax + weighted aggregation (layer 2) ----------
// Wave per node (4 nodes/block), single head, 64 dims, fp32 out.

__global__ __launch_bounds__(256) void spmm2_kernel(const _Float16* __restrict__ feat,
                                                    const float* __restrict__ el,
                                                    const float* __restrict__ er,
                                                    const int* __restrict__ offs,
                                                    const int* __restrict__ ssorted,
                                                    float* __restrict__ out) {
    int n = blockIdx.x * 4 + (threadIdx.x >> 6);
    if (n >= NNODES) return;
    int l = threadIdx.x & 63;
    int e8 = l >> 3, li = l & 7;
    int start = offs[n], end = offs[n + 1];
    int cnt = end - start;
    float ern = er[n];
    const half8* f8 = (const half8*)feat;   // node stride 8 half8s
    float acc[8];
    #pragma unroll
    for (int i = 0; i < 8; ++i) acc[i] = 0.f;
    float s;
    if (cnt <= 64) {
        int sj = 0; float e = -INFINITY;
        if (l < cnt) {
            sj = ssorted[start + l];
            float t = el[sj] + ern;
            e = t > 0.f ? t : NEG_SLOPE * t;
        }
        float m = e;
        #pragma unroll
        for (int o = 1; o < 64; o <<= 1) m = fmaxf(m, __shfl_xor(m, o));
        float p = (l < cnt) ? __expf(e - m) : 0.f;
        s = p;
        #pragma unroll
        for (int o = 1; o < 64; o <<= 1) s += __shfl_xor(s, o);
        for (int j = 0; j < cnt; j += 8) {
            int jj = j + e8;
            int sb = __shfl(sj, jj);
            float wb = __shfl(p, jj);
            half8 f = f8[(size_t)sb * 8 + li];
            #pragma unroll
            for (int i = 0; i < 8; ++i) acc[i] = fmaf(wb, (float)f[i], acc[i]);
        }
    } else {
        float m = -INFINITY;
        for (int b = start + l; b < end; b += 64) {
            int sj2 = ssorted[b];
            float t = el[sj2] + ern;
            t = t > 0.f ? t : NEG_SLOPE * t;
            m = fmaxf(m, t);
        }
        #pragma unroll
        for (int o = 1; o < 64; o <<= 1) m = fmaxf(m, __shfl_xor(m, o));
        s = 0.f;
        for (int base = start; base < end; base += 64) {
            int c = min(64, end - base);
            int sj2 = 0; float p = 0.f;
            if (l < c) {
                sj2 = ssorted[base + l];
                float t = el[sj2] + ern;
                t = t > 0.f ? t : NEG_SLOPE * t;
                p = __expf(t - m);
            }
            s += p;
            for (int j = 0; j < c; j += 8) {
                int jj = j + e8;
                int sb = __shfl(sj2, jj);
                float wb = __shfl(p, jj);
                half8 f = f8[(size_t)sb * 8 + li];
                #pragma unroll
                for (int i = 0; i < 8; ++i) acc[i] = fmaf(wb, (float)f[i], acc[i]);
            }
        }
        #pragma unroll
        for (int o = 1; o < 64; o <<= 1) s += __shfl_xor(s, o);
    }
    #pragma unroll
    for (int o = 8; o < 64; o <<= 1) {
        #pragma unroll
        for (int i = 0; i < 8; ++i) acc[i] += __shfl_xor(acc[i], o);
    }
    if (e8 == 0) {
        float inv = s > 0.f ? 1.f / s : 0.f;
        float4 o0, o1;
        o0.x = acc[0] * inv; o0.y = acc[1] * inv;
        o0.z = acc[2] * inv; o0.w = acc[3] * inv;
        o1.x = acc[4] * inv; o1.y = acc[5] * inv;
        o1.z = acc[6] * inv; o1.w = acc[7] * inv;
        float4* op = (float4*)(out + (size_t)n * 64 + li * 8);
        op[0] = o0; op[1] = o1;
    }
}

// ---------------- launch ----------------

extern "C" void kernel_launch(void* const* d_in, const int* in_sizes, int n_in,
                              void* d_out, int out_size, void* d_ws, size_t ws_size,
                              hipStream_t stream) {
    const float* x   = (const float*)d_in[0];
    const int*   src = (const int*)d_in[1];
    const int*   dst = (const int*)d_in[2];
    const float* W1  = (const float*)d_in[3];
    const float* al1 = (const float*)d_in[4];
    const float* ar1 = (const float*)d_in[5];
    const float* W2  = (const float*)d_in[6];
    const float* al2 = (const float*)d_in[7];
    const float* ar2 = (const float*)d_in[8];
    float* out = (float*)d_out;

    char* ws = (char*)d_ws;
    size_t off = 0;
    auto alloc = [&](size_t bytes) -> void* {
        void* p = ws + off;
        off += (bytes + 255) & ~(size_t)255;
        return p;
    };
    _Float16* feat1 = (_Float16*)alloc((size_t)NNODES * 256 * 2);   // 25.6 MB
    _Float16* h1    = (_Float16*)alloc((size_t)NNODES * 256 * 2);   // 25.6 MB
    _Float16* W1t   = (_Float16*)alloc((size_t)256 * 256 * 2);
    _Float16* W2t   = (_Float16*)alloc((size_t)64 * 256 * 2);
    float* el1    = (float*)alloc((size_t)HEADS * NNODES * 4);      // head-major [4][N]
    float* er1    = (float*)alloc((size_t)HEADS * NNODES * 4);
    float* el2    = (float*)alloc((size_t)NNODES * 4);
    float* er2    = (float*)alloc((size_t)NNODES * 4);
    int* deg      = (int*)alloc((size_t)NNODES * 4);
    int* cursor   = (int*)alloc((size_t)NNODES * 4);
    int* offs     = (int*)alloc((size_t)(NNODES + 1) * 4);
    int* bsums    = (int*)alloc((size_t)NB * 4);
    int* ssorted  = (int*)alloc((size_t)NEDGES * 4);
    _Float16* feat2 = feat1;   // feat1 dead after spmm1; reuse for layer 2

    // --- CSR build ---
    hipMemsetAsync(deg, 0, (size_t)NNODES * 4, stream);
    hipMemsetAsync(cursor, 0, (size_t)NNODES * 4, stream);
    hist_kernel<<<(NEDGES + 255) / 256, 256, 0, stream>>>(dst, deg);
    bsum_kernel<<<NB, 256, 0, stream>>>(deg, bsums);
    scan_write_kernel<<<NB, 256, 0, stream>>>(deg, bsums, offs);
    scatter_kernel<<<(NEDGES + 255) / 256, 256, 0, stream>>>(src, dst, offs, cursor, ssorted);

    // --- weight conversions ---
    convert_wt_kernel<<<(256 * 256 + 255) / 256, 256, 0, stream>>>(W1, W1t, 256, 256);
    convert_wt_kernel<<<(256 * 64 + 255) / 256, 256, 0, stream>>>(W2, W2t, 256, 64);

    // --- Layer 1: fp16 GEMM + fused head-major el/er; fused-softmax SpMM ---
    gemm_f16_kernel<128, false, 1><<<dim3(256 / 128, (NNODES + 127) / 128), 256, 0, stream>>>(
        x, nullptr, W1t, feat1, al1, ar1, el1, er1, NNODES, 256);
    spmm1_kernel<<<NNODES, 256, 0, stream>>>(
        feat1, el1, er1, offs, ssorted, h1);

    // --- Layer 2: fp16 GEMM + fused single-head el/er; fused-softmax SpMM ---
    gemm_f16_kernel<64, true, 2><<<dim3(64 / 64, (NNODES + 127) / 128), 256, 0, stream>>>(
        nullptr, h1, W2t, feat2, al2, ar2, el2, er2, NNODES, 64);
    spmm2_kernel<<<(NNODES + 3) / 4, 256, 0, stream>>>(
        feat2, el2, er2, offs, ssorted, out);
}

// Round 3
// 377.923 us; speedup vs baseline: 1.1535x; 1.0270x over previous
//
#include <hip/hip_runtime.h>
#include <math.h>

#define NNODES 50000
#define NEDGES 800000
#define INDIM 256
#define HID 64
#define HEADS 4
#define OUTDIM 64
#define NEG_SLOPE 0.2f
#define NB ((NNODES + 1023) / 1024)   // 49 scan blocks

typedef __attribute__((ext_vector_type(4))) float f32x4;
typedef _Float16 __attribute__((ext_vector_type(4))) half4;
typedef _Float16 __attribute__((ext_vector_type(8))) half8;

// ---------------- CSR build ----------------

__global__ __launch_bounds__(256) void hist_kernel(const int* __restrict__ dst,
                                                   int* __restrict__ deg) {
    int i = blockIdx.x * 256 + threadIdx.x;
    if (i < NEDGES) atomicAdd(&deg[dst[i]], 1);
}

__global__ __launch_bounds__(256) void bsum_kernel(const int* __restrict__ deg,
                                                   int* __restrict__ bsums) {
    int b = blockIdx.x, t = threadIdx.x;
    int base = b * 1024 + t * 4;
    int s = 0;
    #pragma unroll
    for (int e = 0; e < 4; ++e) { int i = base + e; if (i < NNODES) s += deg[i]; }
    #pragma unroll
    for (int o = 32; o; o >>= 1) s += __shfl_xor(s, o);
    __shared__ int ws[4];
    int lane = t & 63, wid = t >> 6;
    if (lane == 0) ws[wid] = s;
    __syncthreads();
    if (t == 0) bsums[b] = ws[0] + ws[1] + ws[2] + ws[3];
}

__global__ __launch_bounds__(256) void scan_write_kernel(const int* __restrict__ deg,
                                                         const int* __restrict__ bsums,
                                                         int* __restrict__ offs) {
    int b = blockIdx.x, t = threadIdx.x;
    int lane = t & 63, wid = t >> 6;
    int bv = (lane < b) ? bsums[lane] : 0;    // b <= NB-1 < 64
    #pragma unroll
    for (int o = 32; o; o >>= 1) bv += __shfl_xor(bv, o);  // block global offset
    int base = b * 1024 + t * 4;
    int v[4]; int tsum = 0;
    #pragma unroll
    for (int e = 0; e < 4; ++e) {
        int i = base + e;
        v[e] = (i < NNODES) ? deg[i] : 0;
        tsum += v[e];
    }
    int p = tsum;
    #pragma unroll
    for (int o = 1; o < 64; o <<= 1) { int u = __shfl_up(p, o); if (lane >= o) p += u; }
    __shared__ int ws[4];
    if (lane == 63) ws[wid] = p;
    __syncthreads();
    int woff = 0;
    for (int i = 0; i < wid; ++i) woff += ws[i];
    int run = bv + woff + p - tsum;           // exclusive prefix for this thread
    #pragma unroll
    for (int e = 0; e < 4; ++e) {
        int i = base + e;
        if (i < NNODES) { offs[i] = run; run += v[e]; }
    }
    if (b == 0 && t == 0) offs[NNODES] = NEDGES;
}

__global__ __launch_bounds__(256) void scatter_kernel(const int* __restrict__ src,
                                                      const int* __restrict__ dst,
                                                      const int* __restrict__ offs,
                                                      int* __restrict__ cursor,
                                                      int* __restrict__ ssorted) {
    int i = blockIdx.x * 256 + threadIdx.x;
    if (i < NEDGES) {
        int d = dst[i];
        int pos = offs[d] + atomicAdd(&cursor[d], 1);
        ssorted[pos] = src[i];
    }
}

// ---------------- weight transpose -> fp16 ----------------

__global__ __launch_bounds__(256) void convert_wt_kernel(const float* __restrict__ W,
                                                         _Float16* __restrict__ Wt,
                                                         int K, int N) {
    int idx = blockIdx.x * 256 + threadIdx.x;
    if (idx >= K * N) return;
    int k = idx / N, n = idx - k * N;
    Wt[n * K + k] = (_Float16)W[idx];
}

// ---------------- fp16 MFMA GEMM, LDS-free, 128x(BN) tile ----------------

template <int BN, bool AFP16, int ELR>
__global__ __launch_bounds__(256) void gemm_f16_kernel(
        const float* __restrict__ Af, const _Float16* __restrict__ Ah,
        const _Float16* __restrict__ Bt,
        _Float16* __restrict__ C,
        const float* __restrict__ al, const float* __restrict__ ar,
        float* __restrict__ el, float* __restrict__ er,
        int M, int N) {
    constexpr int K = 256;
    constexpr int NT = BN / 32;       // 16-wide n-tiles per wave
    int t = threadIdx.x;
    int lane = t & 63, w = t >> 6;
    int wm = w >> 1, wn = w & 1;
    int lr = lane & 15, quad = lane >> 4;
    int m0 = blockIdx.y * 128, n0 = blockIdx.x * BN;

    f32x4 acc[4][NT];
    #pragma unroll
    for (int i = 0; i < 4; ++i)
        #pragma unroll
        for (int j = 0; j < NT; ++j) acc[i][j] = (f32x4){0.f, 0.f, 0.f, 0.f};

    int arow[4];
    #pragma unroll
    for (int i = 0; i < 4; ++i) {
        int r = m0 + wm * 64 + i * 16 + lr;
        arow[i] = (r < M) ? r : (M - 1);
    }
    int brow[NT];
    #pragma unroll
    for (int j = 0; j < NT; ++j) brow[j] = n0 + wn * NT * 16 + j * 16 + lr;

    #pragma unroll
    for (int kk = 0; kk < K; kk += 32) {
        half8 a[4], b[NT];
        if (AFP16) {
            #pragma unroll
            for (int i = 0; i < 4; ++i)
                a[i] = *(const half8*)(Ah + (size_t)arow[i] * K + kk + quad * 8);
        } else {
            #pragma unroll
            for (int i = 0; i < 4; ++i) {
                const float* ap = Af + (size_t)arow[i] * K + kk + quad * 8;
                float4 f0 = *(const float4*)ap;
                float4 f1 = *(const float4*)(ap + 4);
                a[i][0] = (_Float16)f0.x; a[i][1] = (_Float16)f0.y;
                a[i][2] = (_Float16)f0.z; a[i][3] = (_Float16)f0.w;
                a[i][4] = (_Float16)f1.x; a[i][5] = (_Float16)f1.y;
                a[i][6] = (_Float16)f1.z; a[i][7] = (_Float16)f1.w;
            }
        }
        #pragma unroll
        for (int j = 0; j < NT; ++j)
            b[j] = *(const half8*)(Bt + (size_t)brow[j] * K + kk + quad * 8);
        #pragma unroll
        for (int i = 0; i < 4; ++i)
            #pragma unroll
            for (int j = 0; j < NT; ++j)
                acc[i][j] = __builtin_amdgcn_mfma_f32_16x16x32_f16(a[i], b[j], acc[i][j], 0, 0, 0);
    }
    #pragma unroll
    for (int i = 0; i < 4; ++i) {
        #pragma unroll
        for (int r = 0; r < 4; ++r) {
            int row = m0 + wm * 64 + i * 16 + quad * 4 + r;
            if (row < M) {
                #pragma unroll
                for (int j = 0; j < NT; ++j)
                    C[(size_t)row * N + n0 + wn * NT * 16 + j * 16 + lr] =
                        (_Float16)acc[i][j][r];
            }
        }
    }
    if constexpr (ELR == 1) {
        int h = n0 / 64 + wn;
        float alh[NT], arh[NT];
        #pragma unroll
        for (int j = 0; j < NT; ++j) {
            alh[j] = al[h * 64 + j * 16 + lr];
            arh[j] = ar[h * 64 + j * 16 + lr];
        }
        #pragma unroll
        for (int i = 0; i < 4; ++i) {
            #pragma unroll
            for (int r = 0; r < 4; ++r) {
                float pel = 0.f, per = 0.f;
                #pragma unroll
                for (int j = 0; j < NT; ++j) {
                    pel = fmaf(acc[i][j][r], alh[j], pel);
                    per = fmaf(acc[i][j][r], arh[j], per);
                }
                #pragma unroll
                for (int o = 1; o < 16; o <<= 1) {
                    pel += __shfl_xor(pel, o);
                    per += __shfl_xor(per, o);
                }
                if (lr == 0) {
                    int row = m0 + wm * 64 + i * 16 + quad * 4 + r;
                    if (row < M) {
                        el[(size_t)h * M + row] = pel;
                        er[(size_t)h * M + row] = per;
                    }
                }
            }
        }
    }
    if constexpr (ELR == 2) {
        __shared__ float elbuf[128], erbuf[128];
        float alv[NT], arv[NT];
        #pragma unroll
        for (int j = 0; j < NT; ++j) {
            alv[j] = al[wn * NT * 16 + j * 16 + lr];
            arv[j] = ar[wn * NT * 16 + j * 16 + lr];
        }
        float pel_s[4][4], per_s[4][4];
        #pragma unroll
        for (int i = 0; i < 4; ++i) {
            #pragma unroll
            for (int r = 0; r < 4; ++r) {
                float pel = 0.f, per = 0.f;
                #pragma unroll
                for (int j = 0; j < NT; ++j) {
                    pel = fmaf(acc[i][j][r], alv[j], pel);
                    per = fmaf(acc[i][j][r], arv[j], per);
                }
                #pragma unroll
                for (int o = 1; o < 16; o <<= 1) {
                    pel += __shfl_xor(pel, o);
                    per += __shfl_xor(per, o);
                }
                pel_s[i][r] = pel; per_s[i][r] = per;
            }
        }
        if (wn == 1 && lr == 0) {
            #pragma unroll
            for (int i = 0; i < 4; ++i)
                #pragma unroll
                for (int r = 0; r < 4; ++r) {
                    int rl = wm * 64 + i * 16 + quad * 4 + r;
                    elbuf[rl] = pel_s[i][r];
                    erbuf[rl] = per_s[i][r];
                }
        }
        __syncthreads();
        if (wn == 0 && lr == 0) {
            #pragma unroll
            for (int i = 0; i < 4; ++i)
                #pragma unroll
                for (int r = 0; r < 4; ++r) {
                    int rl = wm * 64 + i * 16 + quad * 4 + r;
                    int row = m0 + rl;
                    if (row < M) {
                        el[row] = pel_s[i][r] + elbuf[rl];
                        er[row] = per_s[i][r] + erbuf[rl];
                    }
                }
        }
    }
}

// ---------------- fused softmax + weighted aggregation (layer 1) ----------
// R13 (resubmit R14: container flake): latency-bound fix. Compile-time
// unrolled 8-step predicated load phase (all gathers in flight at once,
// fr[8] regs), elg gather issued first so the softmax weight chain
// overlaps the feat gathers.

__global__ __launch_bounds__(256) void spmm1_kernel(const _Float16* __restrict__ feat,
                                                    const float* __restrict__ elh,  // [4][N]
                                                    const float* __restrict__ erh,  // [4][N]
                                                    const int* __restrict__ offs,
                                                    const int* __restrict__ ssorted,
                                                    _Float16* __restrict__ h1) {
    int n = blockIdx.x;
    int g = threadIdx.x >> 6;        // wave = head
    int l = threadIdx.x & 63;
    int e8 = l >> 3, li = l & 7;     // 8 edge slots x 8 half8 chunks (64 dims)
    int start = offs[n], end = offs[n + 1];
    int cnt = end - start;
    const float* elg = elh + (size_t)g * NNODES;
    float erg = erh[(size_t)g * NNODES + n];
    const half8* f8 = (const half8*)feat;   // node stride 32 half8s
    float acc[8];
    #pragma unroll
    for (int i = 0; i < 8; ++i) acc[i] = 0.f;
    float s;
    if (cnt <= 64) {
        int sj = 0;
        if (l < cnt) sj = ssorted[start + l];
        // issue elg gather first: weight chain overlaps feat gathers
        float elv = elg[sj] + erg;        // sj=0 for idle lanes: valid addr
        int nst = (cnt + 7) >> 3;
        half8 fr[8];
        #pragma unroll
        for (int js = 0; js < 8; ++js) {
            if (js < nst) {               // wave-uniform predicate
                int sb = __shfl(sj, js * 8 + e8);
                fr[js] = f8[(size_t)sb * 32 + g * 8 + li];
            }
        }
        float e = -INFINITY;
        if (l < cnt) e = elv > 0.f ? elv : NEG_SLOPE * elv;
        float m = e;
        #pragma unroll
        for (int o = 1; o < 64; o <<= 1) m = fmaxf(m, __shfl_xor(m, o));
        float p = (l < cnt) ? __expf(e - m) : 0.f;
        s = p;
        #pragma unroll
        for (int o = 1; o < 64; o <<= 1) s += __shfl_xor(s, o);
        #pragma unroll
        for (int js = 0; js < 8; ++js) {
            if (js < nst) {
                float wb = __shfl(p, js * 8 + e8);   // p=0 masks idle slots
                #pragma unroll
                for (int i = 0; i < 8; ++i) acc[i] = fmaf(wb, (float)fr[js][i], acc[i]);
            }
        }
    } else {
        // generic two-pass fallback (deg > 64): max pass, then exp+aggregate
        float m = -INFINITY;
        for (int b = start + l; b < end; b += 64) {
            int sj2 = ssorted[b];
            float t = elg[sj2] + erg;
            t = t > 0.f ? t : NEG_SLOPE * t;
            m = fmaxf(m, t);
        }
        #pragma unroll
        for (int o = 1; o < 64; o <<= 1) m = fmaxf(m, __shfl_xor(m, o));
        s = 0.f;
        for (int base = start; base < end; base += 64) {
            int c = min(64, end - base);
            int sj2 = 0; float p = 0.f;
            if (l < c) {
                sj2 = ssorted[base + l];
                float t = elg[sj2] + erg;
                t = t > 0.f ? t : NEG_SLOPE * t;
                p = __expf(t - m);
            }
            s += p;
            for (int j = 0; j < c; j += 8) {
                int jj = j + e8;
                int sb = __shfl(sj2, jj);
                float wb = __shfl(p, jj);
                half8 f = f8[(size_t)sb * 32 + g * 8 + li];
                #pragma unroll
                for (int i = 0; i < 8; ++i) acc[i] = fmaf(wb, (float)f[i], acc[i]);
            }
        }
        #pragma unroll
        for (int o = 1; o < 64; o <<= 1) s += __shfl_xor(s, o);
    }
    // reduce the 8 edge-slot partials (lanes differing in bits 3..5)
    #pragma unroll
    for (int o = 8; o < 64; o <<= 1) {
        #pragma unroll
        for (int i = 0; i < 8; ++i) acc[i] += __shfl_xor(acc[i], o);
    }
    if (e8 == 0) {
        float inv = s > 0.f ? 1.f / s : 0.f;
        half8 hv;
        #pragma unroll
        for (int i = 0; i < 8; ++i) {
            float v = acc[i] * inv;
            v = v > 0.f ? v : __expf(v) - 1.f;   // ELU
            hv[i] = (_Float16)v;
        }
        *(half8*)&h1[(size_t)n * 256 + g * 64 + li * 8] = hv;
    }
}

// ---------------- fused softmax + weighted aggregation (layer 2) ----------
// Wave per node (4 nodes/block), single head, 64 dims, fp32 out.
// Same unrolled-prefetch structure as spmm1.

__global__ __launch_bounds__(256) void spmm2_kernel(const _Float16* __restrict__ feat,
                                                    const float* __restrict__ el,
                                                    const float* __restrict__ er,
                                                    const int* __restrict__ offs,
                                                    const int* __restrict__ ssorted,
                                                    float* __restrict__ out) {
    int n = blockIdx.x * 4 + (threadIdx.x >> 6);
    if (n >= NNODES) return;
    int l = threadIdx.x & 63;
    int e8 = l >> 3, li = l & 7;
    int start = offs[n], end = offs[n + 1];
    int cnt = end - start;
    float ern = er[n];
    const half8* f8 = (const half8*)feat;   // node stride 8 half8s
    float acc[8];
    #pragma unroll
    for (int i = 0; i < 8; ++i) acc[i] = 0.f;
    float s;
    if (cnt <= 64) {
        int sj = 0;
        if (l < cnt) sj = ssorted[start + l];
        float elv = el[sj] + ern;
        int nst = (cnt + 7) >> 3;
        half8 fr[8];
        #pragma unroll
        for (int js = 0; js < 8; ++js) {
            if (js < nst) {
                int sb = __shfl(sj, js * 8 + e8);
                fr[js] = f8[(size_t)sb * 8 + li];
            }
        }
        float e = -INFINITY;
        if (l < cnt) e = elv > 0.f ? elv : NEG_SLOPE * elv;
        float m = e;
        #pragma unroll
        for (int o = 1; o < 64; o <<= 1) m = fmaxf(m, __shfl_xor(m, o));
        float p = (l < cnt) ? __expf(e - m) : 0.f;
        s = p;
        #pragma unroll
        for (int o = 1; o < 64; o <<= 1) s += __shfl_xor(s, o);
        #pragma unroll
        for (int js = 0; js < 8; ++js) {
            if (js < nst) {
                float wb = __shfl(p, js * 8 + e8);
                #pragma unroll
                for (int i = 0; i < 8; ++i) acc[i] = fmaf(wb, (float)fr[js][i], acc[i]);
            }
        }
    } else {
        float m = -INFINITY;
        for (int b = start + l; b < end; b += 64) {
            int sj2 = ssorted[b];
            float t = el[sj2] + ern;
            t = t > 0.f ? t : NEG_SLOPE * t;
            m = fmaxf(m, t);
        }
        #pragma unroll
        for (int o = 1; o < 64; o <<= 1) m = fmaxf(m, __shfl_xor(m, o));
        s = 0.f;
        for (int base = start; base < end; base += 64) {
            int c = min(64, end - base);
            int sj2 = 0; float p = 0.f;
            if (l < c) {
                sj2 = ssorted[base + l];
                float t = el[sj2] + ern;
                t = t > 0.f ? t : NEG_SLOPE * t;
                p = __expf(t - m);
            }
            s += p;
            for (int j = 0; j < c; j += 8) {
                int jj = j + e8;
                int sb = __shfl(sj2, jj);
                float wb = __shfl(p, jj);
                half8 f = f8[(size_t)sb * 8 + li];
                #pragma unroll
                for (int i = 0; i < 8; ++i) acc[i] = fmaf(wb, (float)f[i], acc[i]);
            }
        }
        #pragma unroll
        for (int o = 1; o < 64; o <<= 1) s += __shfl_xor(s, o);
    }
    #pragma unroll
    for (int o = 8; o < 64; o <<= 1) {
        #pragma unroll
        for (int i = 0; i < 8; ++i) acc[i] += __shfl_xor(acc[i], o);
    }
    if (e8 == 0) {
        float inv = s > 0.f ? 1.f / s : 0.f;
        float4 o0, o1;
        o0.x = acc[0] * inv; o0.y = acc[1] * inv;
        o0.z = acc[2] * inv; o0.w = acc[3] * inv;
        o1.x = acc[4] * inv; o1.y = acc[5] * inv;
        o1.z = acc[6] * inv; o1.w = acc[7] * inv;
        float4* op = (float4*)(out + (size_t)n * 64 + li * 8);
        op[0] = o0; op[1] = o1;
    }
}

// ---------------- launch ----------------

extern "C" void kernel_launch(void* const* d_in, const int* in_sizes, int n_in,
                              void* d_out, int out_size, void* d_ws, size_t ws_size,
                              hipStream_t stream) {
    const float* x   = (const float*)d_in[0];
    const int*   src = (const int*)d_in[1];
    const int*   dst = (const int*)d_in[2];
    const float* W1  = (const float*)d_in[3];
    const float* al1 = (const float*)d_in[4];
    const float* ar1 = (const float*)d_in[5];
    const float* W2  = (const float*)d_in[6];
    const float* al2 = (const float*)d_in[7];
    const float* ar2 = (const float*)d_in[8];
    float* out = (float*)d_out;

    char* ws = (char*)d_ws;
    size_t off = 0;
    auto alloc = [&](size_t bytes) -> void* {
        void* p = ws + off;
        off += (bytes + 255) & ~(size_t)255;
        return p;
    };
    _Float16* feat1 = (_Float16*)alloc((size_t)NNODES * 256 * 2);   // 25.6 MB
    _Float16* h1    = (_Float16*)alloc((size_t)NNODES * 256 * 2);   // 25.6 MB
    _Float16* W1t   = (_Float16*)alloc((size_t)256 * 256 * 2);
    _Float16* W2t   = (_Float16*)alloc((size_t)64 * 256 * 2);
    float* el1    = (float*)alloc((size_t)HEADS * NNODES * 4);      // head-major [4][N]
    float* er1    = (float*)alloc((size_t)HEADS * NNODES * 4);
    float* el2    = (float*)alloc((size_t)NNODES * 4);
    float* er2    = (float*)alloc((size_t)NNODES * 4);
    int* deg      = (int*)alloc((size_t)NNODES * 4);
    int* cursor   = (int*)alloc((size_t)NNODES * 4);
    int* offs     = (int*)alloc((size_t)(NNODES + 1) * 4);
    int* bsums    = (int*)alloc((size_t)NB * 4);
    int* ssorted  = (int*)alloc((size_t)NEDGES * 4);
    _Float16* feat2 = feat1;   // feat1 dead after spmm1; reuse for layer 2

    // --- CSR build ---
    hipMemsetAsync(deg, 0, (size_t)NNODES * 4, stream);
    hipMemsetAsync(cursor, 0, (size_t)NNODES * 4, stream);
    hist_kernel<<<(NEDGES + 255) / 256, 256, 0, stream>>>(dst, deg);
    bsum_kernel<<<NB, 256, 0, stream>>>(deg, bsums);
    scan_write_kernel<<<NB, 256, 0, stream>>>(deg, bsums, offs);
    scatter_kernel<<<(NEDGES + 255) / 256, 256, 0, stream>>>(src, dst, offs, cursor, ssorted);

    // --- weight conversions ---
    convert_wt_kernel<<<(256 * 256 + 255) / 256, 256, 0, stream>>>(W1, W1t, 256, 256);
    convert_wt_kernel<<<(256 * 64 + 255) / 256, 256, 0, stream>>>(W2, W2t, 256, 64);

    // --- Layer 1: fp16 GEMM + fused head-major el/er; fused-softmax SpMM ---
    gemm_f16_kernel<128, false, 1><<<dim3(256 / 128, (NNODES + 127) / 128), 256, 0, stream>>>(
        x, nullptr, W1t, feat1, al1, ar1, el1, er1, NNODES, 256);
    spmm1_kernel<<<NNODES, 256, 0, stream>>>(
        feat1, el1, er1, offs, ssorted, h1);

    // --- Layer 2: fp16 GEMM + fused single-head el/er; fused-softmax SpMM ---
    gemm_f16_kernel<64, true, 2><<<dim3(64 / 64, (NNODES + 127) / 128), 256, 0, stream>>>(
        nullptr, h1, W2t, feat2, al2, ar2, el2, er2, NNODES, 64);
    spmm2_kernel<<<(NNODES + 3) / 4, 256, 0, stream>>>(
        feat2, el2, er2, offs, ssorted, out);
}